// Round 11
// baseline (231.312 us; speedup 1.0000x reference)
//
#include <hip/hip_runtime.h>

#define NPIX 4096
#define SCALE 0.125f

typedef _Float16 half8 __attribute__((ext_vector_type(8)));
typedef _Float16 half4 __attribute__((ext_vector_type(4)));
typedef float floatx4 __attribute__((ext_vector_type(4)));

// async global->LDS, 16B per lane. lds base must be wave-uniform; data lands
// at base + lane*16 (gfx950 semantics, learn_hip m97/m104).
__device__ __forceinline__ void async16(void* lds, const void* g) {
  __builtin_amdgcn_global_load_lds(
      (const __attribute__((address_space(1))) unsigned int*)(uintptr_t)g,
      (__attribute__((address_space(3))) unsigned int*)(unsigned)(uintptr_t)lds,
      16, 0, 0);
}

// counted vmem wait (T4): n is wave-uniform; literal immediates per branch.
__device__ __forceinline__ void vmwait(int n) {
  if (n >= 6)      asm volatile("s_waitcnt vmcnt(6)" ::: "memory");
  else if (n >= 4) asm volatile("s_waitcnt vmcnt(4)" ::: "memory");
  else             asm volatile("s_waitcnt vmcnt(0)" ::: "memory");
}

// raw s_barrier is NOT a compiler memory fence (round-8 race, rule #18):
// sched_barrier(0) on both sides pins the scheduling region boundary.
__device__ __forceinline__ void pipe_barrier(int n) {
  __builtin_amdgcn_sched_barrier(0);
  vmwait(n);
  __builtin_amdgcn_s_barrier();
  __builtin_amdgcn_sched_barrier(0);
}

// ---------------------------------------------------------------------------
// PREP (one dispatch, role by blockIdx.z) -- proven in round 7:
//   z < 16 : x[b][256][4096] fp32 -> xt[b][4096][256] fp16 transpose
//   z == 16: split w_qkv fp32 -> hi/lo fp16 (768*256 elems over 256 blocks)
// ---------------------------------------------------------------------------
__global__ __launch_bounds__(256) void prep_kernel(const float* __restrict__ x,
                                                   _Float16* __restrict__ xt,
                                                   const float* __restrict__ w_qkv,
                                                   _Float16* __restrict__ wq_hi,
                                                   _Float16* __restrict__ wq_lo) {
  const int tid = threadIdx.x;
  if (blockIdx.z == 16) {
    int base = (blockIdx.x * 4 + blockIdx.y) * 256 + tid;  // 0..65535
#pragma unroll
    for (int r = 0; r < 3; r++) {
      int i = base + r * 65536;  // 3*65536 = 196608 = 768*256
      float v = w_qkv[i];
      _Float16 h = (_Float16)v;
      wq_hi[i] = h;
      wq_lo[i] = (_Float16)(v - (float)h);
    }
    return;
  }
  __shared__ float t[64][65];
  const int n0 = blockIdx.x * 64, c0 = blockIdx.y * 64, b = blockIdx.z;
  const float* xp = x + (long)b * 256 * NPIX;
  const int r = tid >> 4, c4 = (tid & 15) * 4;
#pragma unroll
  for (int p = 0; p < 4; p++) {
    float4 v = *(const float4*)&xp[(long)(c0 + r + p * 16) * NPIX + n0 + c4];
    t[r + p * 16][c4 + 0] = v.x;
    t[r + p * 16][c4 + 1] = v.y;
    t[r + p * 16][c4 + 2] = v.z;
    t[r + p * 16][c4 + 3] = v.w;
  }
  __syncthreads();
  const int n = tid >> 2, cg = (tid & 3) * 16;
  alignas(16) _Float16 o[16];
#pragma unroll
  for (int i = 0; i < 16; i++) o[i] = (_Float16)t[cg + i][n];
  _Float16* dst = &xt[((long)b * NPIX + n0 + n) * 256 + c0 + cg];
  *(float4*)dst = *(float4*)&o[0];
  *(float4*)(dst + 8) = *(float4*)&o[8];
}

// ---------------------------------------------------------------------------
// FUSED k/v GEMM (single-fp16 A) + exp(k)@v^T context partials. 3-DEEP
// counted-vmcnt pipeline; 48 KB union (3 blocks/CU).
// Byte-identical to rounds 9/10 (passed twice, absmax 6.1e-5).
// ---------------------------------------------------------------------------
#define CPB 2
__global__ __launch_bounds__(256) void kv_ctx_gemm(const _Float16* __restrict__ Ahp,
                                                   const _Float16* __restrict__ Bt,
                                                   float* __restrict__ pbuf,
                                                   float* __restrict__ rsbuf) {
  union alignas(16) KVU {
    _Float16 st[3][2][128 * 32];  // [buf][A,B] 48 KB 3-deep staging
    _Float16 ev[128][136];        // 34.8 KB epilogue: rows 0..63 exp(k), 64..127 v
  };
  __shared__ KVU u;
  const int tid = threadIdx.x;
  const int cg = blockIdx.x;     // 0..15 chunk-group (2 chunks of 128 each)
  const int hi = blockIdx.y;     // head 0..3
  const int b = blockIdx.z;
  const _Float16* Bp = Bt + (long)b * NPIX * 256;
  const int wv = tid >> 6, l = tid & 63;
  const int r16 = l & 15, q = l >> 4;
  const int mb = (wv >> 1) * 64, nb = (wv & 1) * 64;
  const int r1 = tid >> 2;
  const int o1 = ((tid & 3) * 8) ^ (((r1 >> 1) & 3) * 8);
  const int ldsc1 = (wv * 64) * 8;
  const int ldsc2 = (256 + wv * 64) * 8;
  const int q8 = (q * 8) ^ (((r16 >> 1) & 3) * 8);
  const long gAk = (long)(256 + hi * 64 + r1) * 256;
  const long gAv = (long)(512 + hi * 64 + r1) * 256;

  auto STAGE = [&](int buf, int kt, int n0) {
    const int k0 = kt * 32;
    async16(&u.st[buf][0][ldsc1], &Ahp[gAk + k0 + o1]);
    async16(&u.st[buf][0][ldsc2], &Ahp[gAv + k0 + o1]);
    async16(&u.st[buf][1][ldsc1], &Bp[(long)(n0 + r1) * 256 + k0 + o1]);
    async16(&u.st[buf][1][ldsc2], &Bp[(long)(n0 + 64 + r1) * 256 + k0 + o1]);
  };

  floatx4 c2[4];
#pragma unroll
  for (int j = 0; j < 4; j++) c2[j] = (floatx4){0.f, 0.f, 0.f, 0.f};
  float rs = 0.f;

  for (int cs = 0; cs < CPB; cs++) {
    const int n0 = (cg * CPB + cs) * 128;
    floatx4 acc[4][4];
#pragma unroll
    for (int i = 0; i < 4; i++)
#pragma unroll
      for (int j = 0; j < 4; j++) acc[i][j] = (floatx4){0.f, 0.f, 0.f, 0.f};

    STAGE(0, 0, n0);
    STAGE(1, 1, n0);
    pipe_barrier(4);  // stage0 landed (stage1 in flight)
    int cc = 0;
    for (int kt = 0; kt < 8; kt++) {
      if (kt < 6) {
        int sb = cc + 2;
        if (sb >= 3) sb -= 3;
        STAGE(sb, kt + 2, n0);
      }
      half8 fa[4], fb[4];
#pragma unroll
      for (int i = 0; i < 4; i++) {
        fa[i] = *(const half8*)&u.st[cc][0][(mb + i * 16 + r16) * 32 + q8];
        fb[i] = *(const half8*)&u.st[cc][1][(nb + i * 16 + r16) * 32 + q8];
      }
#pragma unroll
      for (int i = 0; i < 4; i++)
#pragma unroll
        for (int j = 0; j < 4; j++)
          acc[i][j] = __builtin_amdgcn_mfma_f32_16x16x32_f16(fa[i], fb[j], acc[i][j], 0, 0, 0);
      pipe_barrier(kt < 6 ? 4 : 0);
      cc = (cc == 2) ? 0 : cc + 1;
    }

    const bool is_k = (mb == 0);
#pragma unroll
    for (int i = 0; i < 4; i++) {
      const int row = mb + i * 16 + q * 4;
#pragma unroll
      for (int j = 0; j < 4; j++) {
        const int col = nb + j * 16 + r16;
#pragma unroll
        for (int t = 0; t < 4; t++) {
          const float vv0 = acc[i][j][t];
          u.ev[row + t][col] = (_Float16)(is_k ? __expf(vv0) : vv0);
        }
      }
    }
    __syncthreads();

#pragma unroll
    for (int ks = 0; ks < 4; ks++) {
      half8 a = *(const half8*)&u.ev[wv * 16 + r16][ks * 32 + q * 8];
#pragma unroll
      for (int ii = 0; ii < 8; ii++) rs += (float)a[ii];
#pragma unroll
      for (int j = 0; j < 4; j++) {
        half8 bv = *(const half8*)&u.ev[64 + j * 16 + r16][ks * 32 + q * 8];
        c2[j] = __builtin_amdgcn_mfma_f32_16x16x32_f16(a, bv, c2[j], 0, 0, 0);
      }
    }
    __syncthreads();  // ev reads done before next chunk's STAGE overwrites
  }

  rs += __shfl_xor(rs, 16, 64);
  rs += __shfl_xor(rs, 32, 64);
  const int bh = b * 4 + hi;
  float* pp = pbuf + ((long)bh * 16 + cg) * 4096;
#pragma unroll
  for (int j = 0; j < 4; j++)
#pragma unroll
    for (int reg = 0; reg < 4; reg++)
      pp[(wv * 16 + q * 4 + reg) * 64 + j * 16 + r16] = c2[j][reg];
  if (l < 16) rsbuf[((long)bh * 16 + cg) * 64 + wv * 16 + r16] = rs;
}

// ---------------------------------------------------------------------------
// FUSED reduce_ctx + zinv + mctx (unchanged, passed):
//   M_b[c][h*64+d] = SCALE * kinvz[d] * sum_e w_out[c][h*64+e] * ctx[d][e]
// ---------------------------------------------------------------------------
__global__ __launch_bounds__(256) void mctx_fused(const float* __restrict__ w_out,
                                                  const float* __restrict__ pbuf,
                                                  const float* __restrict__ rsbuf,
                                                  _Float16* __restrict__ Mhi,
                                                  _Float16* __restrict__ Mlo) {
  __shared__ float sctxT[64][65];  // [e][d], +1 pad
  __shared__ float sinv[64];
  const int cq = blockIdx.x, h = blockIdx.y, b = blockIdx.z;
  const int bh = b * 4 + h;
  const float* pp = pbuf + (long)bh * 16 * 4096;
  const int tid = threadIdx.x;
  {
    const int d = tid >> 2, e0 = (tid & 3) * 16;
    float s0[16];
#pragma unroll
    for (int i = 0; i < 16; i++) s0[i] = 0.f;
    for (int c = 0; c < 16; c++) {
#pragma unroll
      for (int k = 0; k < 4; k++) {
        float4 v = *(const float4*)&pp[(long)c * 4096 + d * 64 + e0 + k * 4];
        s0[k * 4 + 0] += v.x;
        s0[k * 4 + 1] += v.y;
        s0[k * 4 + 2] += v.z;
        s0[k * 4 + 3] += v.w;
      }
    }
#pragma unroll
    for (int i = 0; i < 16; i++) sctxT[e0 + i][d] = s0[i];
  }
  if (tid < 64) {
    const float* rp = rsbuf + (long)bh * 16 * 64 + tid;
    float z = 0.f;
#pragma unroll
    for (int c = 0; c < 16; c++) z += rp[c * 64];
    sinv[tid] = 1.0f / z;
  }
  __syncthreads();
  const int c = cq * 64 + (tid >> 2);
  const int d0 = (tid & 3) * 16;
  const float* wp = w_out + (long)c * 256 + h * 64;
  float acc[16];
#pragma unroll
  for (int i = 0; i < 16; i++) acc[i] = 0.f;
#pragma unroll
  for (int e4 = 0; e4 < 16; e4++) {
    float4 wv = *(const float4*)&wp[e4 * 4];
#pragma unroll
    for (int u2 = 0; u2 < 4; u2++) {
      const float we = ((const float*)&wv)[u2];
      const int e = e4 * 4 + u2;
#pragma unroll
      for (int dd = 0; dd < 16; dd++) acc[dd] = fmaf(we, sctxT[e][d0 + dd], acc[dd]);
    }
  }
  alignas(16) _Float16 hi16[16], lo16[16];
#pragma unroll
  for (int k4 = 0; k4 < 4; k4++) {
    float4 zv = *(const float4*)&sinv[d0 + k4 * 4];
#pragma unroll
    for (int u2 = 0; u2 < 4; u2++) {
      const int dd = k4 * 4 + u2;
      float v = acc[dd] * (SCALE * ((const float*)&zv)[u2]);
      _Float16 hh = (_Float16)v;
      hi16[dd] = hh;
      lo16[dd] = (_Float16)(v - (float)hh);
    }
  }
  _Float16* mh = Mhi + ((long)b * 256 + c) * 256 + h * 64 + d0;
  _Float16* ml = Mlo + ((long)b * 256 + c) * 256 + h * 64 + d0;
#pragma unroll
  for (int k = 0; k < 2; k++) {
    *(float4*)&mh[k * 8] = *(float4*)&hi16[k * 8];
    *(float4*)&ml[k * 8] = *(float4*)&lo16[k * 8];
  }
}

// ---------------------------------------------------------------------------
// FUSED q-GEMM + softmax + out-GEMM, v2: A-operands (wq, M -- both small,
// L2-resident, block-shared) are read DIRECTLY from global into registers;
// LDS holds only the B (xt) staging + P tile: 16+64 = 80 KB -> 2 blocks/CU
// (was 144 KB / 1 block). Phase-1 barriers drain only one 8 KB B-prefetch
// issued a full compute phase earlier; phase 2 is barrier-free (P read-only,
// M from global). Arithmetic bit-identical to round 10.
// ---------------------------------------------------------------------------
__global__ __launch_bounds__(512) void qout_fused(const _Float16* __restrict__ wqh,
                                                  const _Float16* __restrict__ wql,
                                                  const _Float16* __restrict__ xt,
                                                  const _Float16* __restrict__ Mhi,
                                                  const _Float16* __restrict__ Mlo,
                                                  const float* __restrict__ bias,
                                                  float* __restrict__ out) {
  struct alignas(16) QO {
    _Float16 Bst[2][128 * 32];  // 16 KB: xt n-tile double-buffer
    _Float16 P[128][256];       // 64 KB: softmax(q), c XOR-swizzled
  };
  __shared__ QO u;
  const int tid = threadIdx.x;
  const int n0 = blockIdx.x * 128;
  const int b = blockIdx.y;
  const _Float16* Bp = xt + (long)b * NPIX * 256;
  const _Float16* MhB = Mhi + (long)b * 65536;
  const _Float16* MlB = Mlo + (long)b * 65536;
  float* Cp = out + (long)b * 256 * NPIX;
  const int wv = tid >> 6, l = tid & 63;
  const int r16 = l & 15, q = l >> 4;
  const int mb = (wv >> 1) * 64;  // 4 m-groups x 64 = 256 c rows
  const int nb = (wv & 1) * 64;   // 2 n-groups x 64 = 128 n cols
  const int r1 = tid >> 2;        // 0..127 (B row)
  const int o1 = ((tid & 3) * 8) ^ (((r1 >> 1) & 3) * 8);
  const int q8 = (q * 8) ^ (((r16 >> 1) & 3) * 8);

  // one async16 per wave: wave w fills Bst rows 16w..16w+15 (1 KB slice)
  auto STAGE_B = [&](int buf, int kt) {
    async16(&u.Bst[buf][wv * 512], &Bp[(long)(n0 + r1) * 256 + kt * 32 + o1]);
  };

  // ---- phase 1: q = (Wq_hi+Wq_lo) @ xt^T, 256 c x 128 n; A from global ----
  floatx4 acc[4][4];
#pragma unroll
  for (int i = 0; i < 4; i++)
#pragma unroll
    for (int j = 0; j < 4; j++) acc[i][j] = (floatx4){0.f, 0.f, 0.f, 0.f};

  STAGE_B(0, 0);
  __syncthreads();
  for (int kt = 0; kt < 8; kt++) {
    const int cur = kt & 1;
    if (kt < 7) STAGE_B(cur ^ 1, kt + 1);
    const long ka = kt * 32 + q * 8;
    half8 fa[4], flo[4], fb[4];
#pragma unroll
    for (int i = 0; i < 4; i++) {
      const long arow = (long)(mb + i * 16 + r16) * 256;
      fa[i] = *(const half8*)&wqh[arow + ka];
      flo[i] = *(const half8*)&wql[arow + ka];
      fb[i] = *(const half8*)&u.Bst[cur][(nb + i * 16 + r16) * 32 + q8];
    }
#pragma unroll
    for (int i = 0; i < 4; i++)
#pragma unroll
      for (int j = 0; j < 4; j++) {
        acc[i][j] = __builtin_amdgcn_mfma_f32_16x16x32_f16(fa[i], fb[j], acc[i][j], 0, 0, 0);
        acc[i][j] = __builtin_amdgcn_mfma_f32_16x16x32_f16(flo[i], fb[j], acc[i][j], 0, 0, 0);
      }
    __syncthreads();  // drains only the single B-prefetch issued above
  }

  // ---- softmax over d (each wave's 64 m-rows = one head) -> P in LDS ----
#pragma unroll
  for (int j = 0; j < 4; j++) {
    float s = 0.f;
#pragma unroll
    for (int i = 0; i < 4; i++)
#pragma unroll
      for (int t = 0; t < 4; t++) {
        float e = __expf(acc[i][j][t]);
        acc[i][j][t] = e;
        s += e;
      }
    s += __shfl_xor(s, 16, 64);
    s += __shfl_xor(s, 32, 64);
    const float rinv = 1.0f / s;
    const int nl = nb + j * 16 + r16;   // 0..127
    const int swz = (nl & 7) * 8;       // XOR on c-bits 3..5 (bijective per half4)
#pragma unroll
    for (int i = 0; i < 4; i++) {
      half4 h4;
#pragma unroll
      for (int t = 0; t < 4; t++) h4[t] = (_Float16)(acc[i][j][t] * rinv);
      *(half4*)&u.P[nl][(mb + i * 16 + q * 4) ^ swz] = h4;
    }
  }
  __syncthreads();  // P visible to all waves

  // ---- phase 2: out = (Mhi+Mlo) @ P + bias; K = 256 c; NO barriers ----
  floatx4 ac2[4][4];
#pragma unroll
  for (int i = 0; i < 4; i++)
#pragma unroll
    for (int j = 0; j < 4; j++) ac2[i][j] = (floatx4){0.f, 0.f, 0.f, 0.f};

  for (int kt = 0; kt < 8; kt++) {
    const int kc = kt * 32 + q * 8;
    half8 fa[4], flo[4], fb[4];
#pragma unroll
    for (int i = 0; i < 4; i++) {
      const long arow = (long)(mb + i * 16 + r16) * 256;
      fa[i] = *(const half8*)&MhB[arow + kc];
      flo[i] = *(const half8*)&MlB[arow + kc];
      const int nrow = nb + i * 16 + r16;
      fb[i] = *(const half8*)&u.P[nrow][kc ^ ((nrow & 7) * 8)];
    }
#pragma unroll
    for (int i = 0; i < 4; i++)
#pragma unroll
      for (int j = 0; j < 4; j++) {
        ac2[i][j] = __builtin_amdgcn_mfma_f32_16x16x32_f16(fa[i], fb[j], ac2[i][j], 0, 0, 0);
        ac2[i][j] = __builtin_amdgcn_mfma_f32_16x16x32_f16(flo[i], fb[j], ac2[i][j], 0, 0, 0);
      }
  }

#pragma unroll
  for (int i = 0; i < 4; i++) {
    const int mrow = mb + i * 16 + q * 4;
#pragma unroll
    for (int t = 0; t < 4; t++) {
      float bz = bias[mrow + t];
#pragma unroll
      for (int j = 0; j < 4; j++) {
        Cp[(long)(mrow + t) * NPIX + n0 + nb + j * 16 + r16] = ac2[i][j][t] + bz;
      }
    }
  }
}

extern "C" void kernel_launch(void* const* d_in, const int* in_sizes, int n_in,
                              void* d_out, int out_size, void* d_ws, size_t ws_size,
                              hipStream_t stream) {
  const float* x = (const float*)d_in[0];      // [16][256][4096]
  const float* w_qkv = (const float*)d_in[1];  // [768][256]
  const float* w_out = (const float*)d_in[2];  // [256][256]
  const float* b_out = (const float*)d_in[3];  // [256]
  float* out = (float*)d_out;                  // [16][256][4096]

  // d_ws layout (out is written by qout_fused, so NO scratch lives in d_out):
  _Float16* xt = (_Float16*)d_ws;                           // [16][4096][256] f16 = 33.5 MB
  float* pbuf = (float*)(xt + (long)16 * NPIX * 256);       // 64bh*16p*4096 f32 = 16.8 MB
  float* rsbuf = pbuf + (long)64 * 16 * 4096;               // 256 KB
  _Float16* wq_hi = (_Float16*)(rsbuf + 64 * 16 * 64);
  _Float16* wq_lo = wq_hi + 768 * 256;
  _Float16* Mhi = wq_lo + 768 * 256;                        // 2 MB
  _Float16* Mlo = Mhi + 16 * 256 * 256;                     // 2 MB

  // prep: transpose (z<16) + w_qkv split (z==16), one dispatch
  prep_kernel<<<dim3(64, 4, 17), 256, 0, stream>>>(x, xt, w_qkv, wq_hi, wq_lo);
  // fused k/v GEMM (single-fp16 A) + exp(k)@v^T context partials
  kv_ctx_gemm<<<dim3(16, 4, 16), 256, 0, stream>>>(wq_hi, xt, pbuf, rsbuf);
  // fused partial-reduce + 1/Z + M_b = w_out @ ctx^T * diag(SCALE*invZ)
  mctx_fused<<<dim3(4, 4, 16), 256, 0, stream>>>(w_out, pbuf, rsbuf, Mhi, Mlo);
  // fused q GEMM + softmax + out GEMM (P never touches HBM; A-ops from L2)
  qout_fused<<<dim3(32, 16), 512, 0, stream>>>(wq_hi, wq_lo, xt, Mhi, Mlo, b_out, out);
}